// Round 9
// baseline (22785.771 us; speedup 1.0000x reference)
//
#include <hip/hip_runtime.h>

#define N 4096
#define NT 730
#define NTH 512
#define PER_T 8                // nodes per thread, post index p = tid*8 + r
#define QLB 1e-4f
#define DT_S 3600.0f
#define SKEL_PASSES 4

// ---- workspace layout (4-byte element offsets) ----
#define WS_DS     0            // int[4096]  parent (node space)
#define WS_SZ     4096         // int[4096]  subtree size (init 1)
#define WS_CCNT   8192         // int[4096]  children counts (node space)
#define WS_COFF   12288        // int[4097]  children CSR offsets (node space)
#define WS_CUR    16388        // int[4096]
#define WS_HI     20484        // int[4096]  node -> post index; init -1
#define WS_FLAG   24580        // int[4096]  (skel sink; dead after)
#define WS_C1     28676        // f32[4096]
#define WS_C2     32772        // f32[4096]
#define WS_C3     36868        // f32[4096]
#define WS_C4     40964        // f32[4096]
#define WS_CLIST  45060        // int[4096]  children list (node space, for k_post)
#define WS_GP     49156        // int[4096]  post -> node id
#define WS_LOP    53252        // int[4096]  post -> subtree lo (post space)
#define WS_C3P    57348        // f32[4096]
#define WS_C4P    61444        // f32[4096]
#define WS_EPAR   65540        // int[4096]  post -> parent post (root: self)
#define WS_EWS    69636        // f32[4096]  post -> c2[parent] (root: 0)
#define WS_SP     73736        // f64[4096]  (8B aligned)
#define WS_ISP    81928        // f64[4096]
#define WS_QPP    90120        // f32[730*4096] permuted q_prime (optional)
#define WS_END    (WS_QPP + NT * N)

__device__ __forceinline__ int qidx(int p) { return ((p & 7) << 9) | (p >> 3); }

// ---- wave64 inclusive scan via DPP (VALU pipe; verified R6/R7, absmax 0.0) ----
template <int CTRL, int RMASK>
__device__ __forceinline__ double dpp_stage(double v) {
    union U { double d; unsigned int u[2]; };
    U s, t;
    s.d = v;
    t.u[0] = (unsigned)__builtin_amdgcn_update_dpp(0, (int)s.u[0], CTRL, RMASK, 0xf, false);
    t.u[1] = (unsigned)__builtin_amdgcn_update_dpp(0, (int)s.u[1], CTRL, RMASK, 0xf, false);
    return v + t.d;
}
__device__ __forceinline__ double wave_incl_scan(double v) {
    v = dpp_stage<0x111, 0xf>(v);   // row_shr:1
    v = dpp_stage<0x112, 0xf>(v);   // row_shr:2
    v = dpp_stage<0x114, 0xf>(v);   // row_shr:4
    v = dpp_stage<0x118, 0xf>(v);   // row_shr:8
    v = dpp_stage<0x142, 0xa>(v);   // row_bcast:15 -> rows 1,3
    v = dpp_stage<0x143, 0xc>(v);   // row_bcast:31 -> rows 2,3
    return v;
}

__global__ void k_init(int* ds, int* sz, int* ccnt, int* hi, int* flag) {
    int j = blockIdx.x * 256 + threadIdx.x;
    if (j < N) { ds[j] = N - 1; sz[j] = 1; ccnt[j] = 0; hi[j] = -1; flag[j] = 0; }
}

__global__ void k_extract(const float4* __restrict__ adj4, int* __restrict__ ds) {
    long idx = (long)blockIdx.x * 256 + threadIdx.x;
    if (idx >= (long)N * N / 4) return;
    float4 w = adj4[idx];
    long base = idx * 4;
    int row = (int)(base >> 12);
    int col = (int)(base & 4095);
    if (w.x != 0.0f) ds[col + 0] = row;
    if (w.y != 0.0f) ds[col + 1] = row;
    if (w.z != 0.0f) ds[col + 2] = row;
    if (w.w != 0.0f) ds[col + 3] = row;
}

__global__ void k_coeffs(const float* n, const float* qs, const float* ps,
                         const float* len, const float* slope, const float* width,
                         const float* xs, float* __restrict__ c1, float* __restrict__ c2,
                         float* __restrict__ c3, float* __restrict__ c4) {
    int i = blockIdx.x * 256 + threadIdx.x;
    if (i >= N) return;
    float s  = fmaxf(slope[i], 1e-4f);
    float dp = logf(width[i] / ps[i]) / logf(qs[i]);
    float v  = (1.0f / n[i]) * powf(dp, 2.0f / 3.0f) * sqrtf(s);
    float c  = fminf(fmaxf(v, 0.3f), 15.0f) * (5.0f / 3.0f);
    float k  = len[i] / c;
    float x  = xs[i];
    float denom = 2.0f * k * (1.0f - x) + DT_S;
    c1[i] = (DT_S - 2.0f * k * x) / denom;
    c2[i] = (DT_S + 2.0f * k * x) / denom;
    c3[i] = (2.0f * k * (1.0f - x) - DT_S) / denom;
    c4[i] = 2.0f * DT_S / denom;
}

__global__ void k_count(const int* __restrict__ ds, int* __restrict__ ccnt,
                        int* __restrict__ sz) {
    int u = blockIdx.x * 256 + threadIdx.x;
    if (u >= N || u == N - 1) return;
    atomicAdd(&ccnt[ds[u]], 1);
    int a = ds[u];
    while (true) {
        atomicAdd(&sz[a], 1);
        if (a == N - 1) break;
        a = ds[a];
    }
}

// single-block exclusive scan of 4096 ints
__global__ __launch_bounds__(1024) void k_scan(const int* __restrict__ src,
                                               int* __restrict__ off,
                                               int* __restrict__ cur) {
    __shared__ int buf[1024];
    int tid = threadIdx.x;
    int a0 = src[tid * 4 + 0], a1 = src[tid * 4 + 1];
    int a2 = src[tid * 4 + 2], a3 = src[tid * 4 + 3];
    int s1 = a0, s2 = a0 + a1, s3 = a0 + a1 + a2, tot = s3 + a3;
    buf[tid] = tot;
    __syncthreads();
    for (int o = 1; o < 1024; o <<= 1) {
        int add = (tid >= o) ? buf[tid - o] : 0;
        __syncthreads();
        buf[tid] += add;
        __syncthreads();
    }
    int base = buf[tid] - tot;
    off[tid * 4 + 0] = base;      cur[tid * 4 + 0] = base;
    off[tid * 4 + 1] = base + s1; cur[tid * 4 + 1] = base + s1;
    off[tid * 4 + 2] = base + s2; cur[tid * 4 + 2] = base + s2;
    off[tid * 4 + 3] = base + s3; cur[tid * 4 + 3] = base + s3;
    if (tid == 1023) off[N] = buf[1023];
}

__global__ void k_fill(const int* __restrict__ ds, int* __restrict__ cur,
                       int* __restrict__ clist) {
    int u = blockIdx.x * 256 + threadIdx.x;
    if (u >= N || u == N - 1) return;
    int cp = atomicAdd(&cur[ds[u]], 1);
    clist[cp] = u;
}

// top-down post-order interval assignment (hi = post index)
__global__ __launch_bounds__(1024) void k_post(const int* __restrict__ ds,
                                               const int* __restrict__ sz,
                                               const int* __restrict__ coff,
                                               const int* __restrict__ ccnt,
                                               const int* __restrict__ clist,
                                               int* __restrict__ hi,
                                               int* __restrict__ flag) {
    int tid = threadIdx.x;
    if (tid == 0) hi[N - 1] = N - 1;
    __syncthreads();
    for (int it = 0; it < 96; ++it) {
        for (int v = tid; v < N; v += 1024) {
            if (hi[v] >= 0 && flag[v] == 0) {
                int cum = hi[v] - sz[v] + 1;
                int b0 = coff[v], e0 = b0 + ccnt[v];
                for (int k = b0; k < e0; ++k) {
                    int c = clist[k];
                    hi[c] = cum + sz[c] - 1;
                    cum += sz[c];
                }
                flag[v] = 1;
            }
        }
        __syncthreads();
    }
}

// post-space arrays: S (ancestor c1 product, f64), lo, coeffs, parent-post, c2[par]
__global__ void k_prep(const int* __restrict__ ds, const int* __restrict__ sz,
                       const int* __restrict__ hi,
                       const float* __restrict__ c1, const float* __restrict__ c2,
                       const float* __restrict__ c3, const float* __restrict__ c4,
                       int* __restrict__ gP, int* __restrict__ loP,
                       float* __restrict__ c3P, float* __restrict__ c4P,
                       int* __restrict__ eparP, float* __restrict__ ewsP,
                       double* __restrict__ SP, double* __restrict__ ISP) {
    int u = blockIdx.x * 256 + threadIdx.x;
    if (u >= N) return;
    int p = hi[u];
    double s = 1.0;
    if (u != N - 1) {
        int a = ds[u];
        while (true) {
            s *= (double)c1[a];
            if (a == N - 1) break;
            a = ds[a];
        }
    }
    SP[p] = s; ISP[p] = 1.0 / s;
    gP[p] = u;
    loP[p] = p - sz[u] + 1;
    c3P[p] = c3[u]; c4P[p] = c4[u];
    if (u != N - 1) {
        eparP[p] = hi[ds[u]];
        ewsP[p] = c2[ds[u]];
    } else {
        eparP[p] = p;        // root: self-scatter with weight 0
        ewsP[p] = 0.0f;
    }
}

// permute q_prime into post order (coalesced write, gathered read)
__global__ void k_permute(const float* __restrict__ qp, const int* __restrict__ gP,
                          float* __restrict__ qpp) {
    long e = (long)blockIdx.x * 256 + threadIdx.x;
    if (e >= (long)NT * N) return;
    int tr = (int)(e >> 12);
    int v  = (int)(e & 4095);
    qpp[e] = qp[(size_t)tr * N + gP[v]];
}

// Persistent single-workgroup routing, 2 barriers/step (R7 verbatim, 4.80ms).
__global__ __launch_bounds__(NTH) void k_route(
    const float* __restrict__ qp, const float* __restrict__ qpp,
    const float* __restrict__ c3g, const float* __restrict__ c4g,
    const int* __restrict__ gPg, const int* __restrict__ loPg,
    const int* __restrict__ eparPg, const float* __restrict__ ewsPg,
    const double* __restrict__ SPg, const double* __restrict__ ISPg,
    int use_perm, float* __restrict__ out) {
    __shared__ float CSA[2][N];             // childsum accumulators (linear post)
    __shared__ double TLp[N];               // within-wave prefix, qidx layout
    __shared__ __align__(16) double wpart[8];
    int tid = threadIdx.x;
    int lane = tid & 63, wid = tid >> 6;

    int epar[PER_T], jg[PER_T], wv[PER_T], g[PER_T];
    float ews[PER_T], c3r[PER_T], c4r[PER_T], qreg[PER_T], qc[PER_T], qn[PER_T];
    double Sr[PER_T], iSr[PER_T];
    bool haslo[PER_T];
#pragma unroll
    for (int r = 0; r < PER_T; ++r) {
        int p = tid * PER_T + r;
        epar[r] = eparPg[p]; ews[r] = ewsPg[p];
        int l = loPg[p];
        haslo[r] = (l > 0);
        int lm = (l > 0) ? (l - 1) : 0;
        jg[r] = qidx(lm);
        wv[r] = lm >> 9;
        g[r] = gPg[p];
        c3r[r] = c3g[p]; c4r[r] = c4g[p];
        Sr[r] = SPg[p]; iSr[r] = ISPg[p];
        float q0 = use_perm ? qpp[p] : qp[g[r]];   // row 0 raw initial state
        qreg[r] = q0; qc[r] = q0;
    }
    {   // zero both CSA buffers
        float4 z = make_float4(0.f, 0.f, 0.f, 0.f);
        float4* c0 = (float4*)&CSA[0][tid * PER_T];
        float4* c1 = (float4*)&CSA[1][tid * PER_T];
        c0[0] = z; c0[1] = z; c1[0] = z; c1[1] = z;
    }
    if (tid == NTH - 1) out[0] = fmaxf(qreg[PER_T - 1], QLB);   // root = post N-1
    __syncthreads();
    // initial scatter of q0 into buffer 1 (consumed by step t=1)
#pragma unroll
    for (int r = 0; r < PER_T; ++r)
        atomicAdd(&CSA[1][epar[r]], ews[r] * qreg[r]);
    __syncthreads();

    for (int t = 1; t < NT; ++t) {
        int s = t & 1;
        // ---- Phase X ----
        float4 ca = *(const float4*)&CSA[s][tid * PER_T];
        float4 cb = *(const float4*)&CSA[s][tid * PER_T + 4];
        float cs[PER_T] = {ca.x, ca.y, ca.z, ca.w, cb.x, cb.y, cb.z, cb.w};
        float bb[PER_T];
        double yv[PER_T], Tloc[PER_T];
        double tl = 0.0;
#pragma unroll
        for (int r = 0; r < PER_T; ++r) {
            bb[r] = cs[r] + c3r[r] * qreg[r] + c4r[r] * fmaxf(qc[r], QLB);
            double y = Sr[r] * (double)bb[r];
            yv[r] = y;
            tl += y;
            Tloc[r] = tl;
        }
        double incl = wave_incl_scan(tl);              // VALU only
        double texw = incl - tl;                       // within-wave excl prefix
#pragma unroll
        for (int r = 0; r < PER_T; ++r)
            TLp[(r << 9) | tid] = texw + Tloc[r];      // partial (no wave offset)
        if (lane == 63) wpart[wid] = incl;
        __syncthreads();                               // B
        // ---- Phase Y ----
        if (t < NT - 1) {                              // prefetch next lateral row
            if (use_perm) {
                const float4* row4 = (const float4*)(qpp + (size_t)t * N);
                float4 a = row4[tid * 2], b = row4[tid * 2 + 1];
                qn[0] = a.x; qn[1] = a.y; qn[2] = a.z; qn[3] = a.w;
                qn[4] = b.x; qn[5] = b.y; qn[6] = b.z; qn[7] = b.w;
            } else {
                const float* row = qp + (size_t)t * N;
#pragma unroll
                for (int r = 0; r < PER_T; ++r) qn[r] = row[g[r]];
            }
        }
        double2 w0 = *(const double2*)&wpart[0];
        double2 w1 = *(const double2*)&wpart[2];
        double2 w2 = *(const double2*)&wpart[4];
        double2 w3 = *(const double2*)&wpart[6];
        double P1 = w0.x, P2 = P1 + w0.y, P3 = P2 + w1.x, P4 = P3 + w1.y;
        double P5 = P4 + w2.x, P6 = P5 + w2.y, P7 = P6 + w3.x;
        double woff = 0.0;                             // own wave offset (uniform)
        if (wid > 0) woff += w0.x;
        if (wid > 1) woff += w0.y;
        if (wid > 2) woff += w1.x;
        if (wid > 3) woff += w1.y;
        if (wid > 4) woff += w2.x;
        if (wid > 5) woff += w2.y;
        if (wid > 6) woff += w3.x;
#pragma unroll
        for (int r = 0; r < PER_T; ++r) {
            int w = wv[r];
            double lo2 = (w & 2) ? ((w & 1) ? P3 : P2) : ((w & 1) ? P1 : 0.0);
            double hi2 = (w & 2) ? ((w & 1) ? P7 : P6) : ((w & 1) ? P5 : P4);
            double goff = (w & 4) ? hi2 : lo2;
            double Tg = haslo[r] ? (TLp[jg[r]] + goff) : 0.0;
            double Tself = woff + texw + Tloc[r] - yv[r];
            double x = (double)bb[r] + (Tself - Tg) * iSr[r];
            qreg[r] = fmaxf((float)x, QLB);
        }
        {   // reset consumed buffer (reused at step t+2)
            float4 z = make_float4(0.f, 0.f, 0.f, 0.f);
            float4* c0 = (float4*)&CSA[s][tid * PER_T];
            c0[0] = z; c0[1] = z;
        }
#pragma unroll
        for (int r = 0; r < PER_T; ++r)                // push into next buffer
            atomicAdd(&CSA[s ^ 1][epar[r]], ews[r] * qreg[r]);
        if (tid == NTH - 1) out[t] = qreg[PER_T - 1];
        __syncthreads();                               // A
#pragma unroll
        for (int r = 0; r < PER_T; ++r) qc[r] = qn[r];
    }
}

// ---- ABLATION PROBE: k_route's exact structure (LDS ops, barriers, VMEM)
// with ALL f64 math removed. 4x729 steps; writes only to ws sink.
__global__ __launch_bounds__(NTH) void k_skel(
    const float* __restrict__ qpp, const float* __restrict__ c3g,
    const float* __restrict__ c4g, const int* __restrict__ loPg,
    const int* __restrict__ eparPg, const float* __restrict__ ewsPg,
    float* __restrict__ sink) {
    __shared__ float CSA[2][N];
    __shared__ double TLp[N];
    __shared__ __align__(16) double wpart[8];
    int tid = threadIdx.x;
    int lane = tid & 63, wid = tid >> 6;

    int epar[PER_T], jg[PER_T];
    float ews[PER_T], c3r[PER_T], c4r[PER_T], qreg[PER_T], qc[PER_T], qn[PER_T];
    bool haslo[PER_T];
#pragma unroll
    for (int r = 0; r < PER_T; ++r) {
        int p = tid * PER_T + r;
        epar[r] = eparPg[p]; ews[r] = ewsPg[p];
        int l = loPg[p];
        haslo[r] = (l > 0);
        jg[r] = qidx((l > 0) ? (l - 1) : 0);
        c3r[r] = c3g[p]; c4r[r] = c4g[p];
        float q0 = qpp[p];
        qreg[r] = q0; qc[r] = q0;
    }
    {
        float4 z = make_float4(0.f, 0.f, 0.f, 0.f);
        float4* c0 = (float4*)&CSA[0][tid * PER_T];
        float4* c1 = (float4*)&CSA[1][tid * PER_T];
        c0[0] = z; c0[1] = z; c1[0] = z; c1[1] = z;
    }
    __syncthreads();
#pragma unroll
    for (int r = 0; r < PER_T; ++r)
        atomicAdd(&CSA[1][epar[r]], ews[r] * qreg[r]);
    __syncthreads();

#pragma unroll 1
    for (int pass = 0; pass < SKEL_PASSES; ++pass) {
#pragma unroll 1
        for (int t = 1; t < NT; ++t) {
            int s = t & 1;
            // ---- Phase X (f32 only) ----
            float4 ca = *(const float4*)&CSA[s][tid * PER_T];
            float4 cb = *(const float4*)&CSA[s][tid * PER_T + 4];
            float cs[PER_T] = {ca.x, ca.y, ca.z, ca.w, cb.x, cb.y, cb.z, cb.w};
            float bb[PER_T];
#pragma unroll
            for (int r = 0; r < PER_T; ++r) {
                bb[r] = cs[r] + c3r[r] * qreg[r] + c4r[r] * fmaxf(qc[r], QLB);
                TLp[(r << 9) | tid] = (double)bb[r];   // same 8 ds_write_b64
            }
            if (lane == 63) wpart[wid] = (double)bb[0];
            __syncthreads();                           // B
            // ---- Phase Y ----
            if (t < NT - 1) {
                const float4* row4 = (const float4*)(qpp + (size_t)t * N);
                float4 a = row4[tid * 2], b = row4[tid * 2 + 1];
                qn[0] = a.x; qn[1] = a.y; qn[2] = a.z; qn[3] = a.w;
                qn[4] = b.x; qn[5] = b.y; qn[6] = b.z; qn[7] = b.w;
            }
            double2 w0 = *(const double2*)&wpart[0];
            double2 w1 = *(const double2*)&wpart[2];
            double2 w2 = *(const double2*)&wpart[4];
            double2 w3 = *(const double2*)&wpart[6];
            float acc = (float)w0.x + (float)w1.x + (float)w2.x + (float)w3.y
                      + (float)w0.y + (float)w1.y + (float)w2.y + (float)w3.x;
            acc *= 1e-30f;                             // keep live, stay bounded
#pragma unroll
            for (int r = 0; r < PER_T; ++r) {
                float Tg = haslo[r] ? (float)TLp[jg[r]] : 0.0f;  // same 8 gathers
                float x = bb[r] + Tg * 1e-30f + acc;
                qreg[r] = fmaxf(x, QLB);
            }
            {
                float4 z = make_float4(0.f, 0.f, 0.f, 0.f);
                float4* c0 = (float4*)&CSA[s][tid * PER_T];
                c0[0] = z; c0[1] = z;
            }
#pragma unroll
            for (int r = 0; r < PER_T; ++r)
                atomicAdd(&CSA[s ^ 1][epar[r]], ews[r] * qreg[r]);
            if (tid == NTH - 1) sink[t & 2047] = qreg[PER_T - 1];
            __syncthreads();                           // A
#pragma unroll
            for (int r = 0; r < PER_T; ++r) qc[r] = qn[r];
        }
    }
}

extern "C" void kernel_launch(void* const* d_in, const int* in_sizes, int n_in,
                              void* d_out, int out_size, void* d_ws, size_t ws_size,
                              hipStream_t stream) {
    const float* qp    = (const float*)d_in[0];   // [730,4096]
    const float* n     = (const float*)d_in[1];
    const float* qs    = (const float*)d_in[2];
    const float* ps    = (const float*)d_in[3];
    const float* len   = (const float*)d_in[4];
    const float* slope = (const float*)d_in[5];
    const float* width = (const float*)d_in[6];
    const float* xs    = (const float*)d_in[7];
    const float* adj   = (const float*)d_in[8];   // [4096,4096]
    float* out = (float*)d_out;

    int*    W     = (int*)d_ws;
    int*    ds    = W + WS_DS;
    int*    sz    = W + WS_SZ;
    int*    ccnt  = W + WS_CCNT;
    int*    coff  = W + WS_COFF;
    int*    cur   = W + WS_CUR;
    int*    hi    = W + WS_HI;
    int*    flag  = W + WS_FLAG;
    float*  c1    = (float*)(W + WS_C1);
    float*  c2    = (float*)(W + WS_C2);
    float*  c3    = (float*)(W + WS_C3);
    float*  c4    = (float*)(W + WS_C4);
    int*    clist = W + WS_CLIST;
    int*    gP    = W + WS_GP;
    int*    loP   = W + WS_LOP;
    float*  c3P   = (float*)(W + WS_C3P);
    float*  c4P   = (float*)(W + WS_C4P);
    int*    eparP = W + WS_EPAR;
    float*  ewsP  = (float*)(W + WS_EWS);
    double* SP    = (double*)(W + WS_SP);
    double* ISP   = (double*)(W + WS_ISP);
    float*  QPP   = (float*)(W + WS_QPP);

    int use_perm = (ws_size >= (size_t)WS_END * 4) ? 1 : 0;

    k_init<<<(N + 255) / 256, 256, 0, stream>>>(ds, sz, ccnt, hi, flag);
    k_extract<<<(N * N / 4 + 255) / 256, 256, 0, stream>>>((const float4*)adj, ds);
    k_coeffs<<<(N + 255) / 256, 256, 0, stream>>>(n, qs, ps, len, slope, width, xs,
                                                  c1, c2, c3, c4);
    k_count<<<(N + 255) / 256, 256, 0, stream>>>(ds, ccnt, sz);
    k_scan<<<1, 1024, 0, stream>>>(ccnt, coff, cur);
    k_fill<<<(N + 255) / 256, 256, 0, stream>>>(ds, cur, clist);
    k_post<<<1, 1024, 0, stream>>>(ds, sz, coff, ccnt, clist, hi, flag);
    k_prep<<<(N + 255) / 256, 256, 0, stream>>>(ds, sz, hi, c1, c2, c3, c4,
                                                gP, loP, c3P, c4P, eparP, ewsP,
                                                SP, ISP);
    if (use_perm)
        k_permute<<<(int)(((long)NT * N + 255) / 256), 256, 0, stream>>>(qp, gP, QPP);
    k_route<<<1, NTH, 0, stream>>>(qp, QPP, c3P, c4P, gP, loP, eparP, ewsP,
                                   SP, ISP, use_perm, out);
    // ablation probe last (reads qpp built above; writes only ws scratch)
    k_skel<<<1, NTH, 0, stream>>>(QPP, c3P, c4P, loP, eparP, ewsP, (float*)flag);
}

// Round 11
// 4914.043 us; speedup vs baseline: 4.6369x; 4.6369x over previous
//
#include <hip/hip_runtime.h>

#define N 4096
#define NT 730
#define NTH 1024
#define PER_T 4                // nodes per thread, post index p = tid*4 + r
#define QLB 1e-4f
#define DT_S 3600.0f

// ---- workspace layout (4-byte element offsets) ----
#define WS_DS     0            // int[4096]  parent (node space)
#define WS_SZ     4096         // int[4096]  subtree size (init 1)
#define WS_CCNT   8192         // int[4096]  children counts (node space)
#define WS_COFF   12288        // int[4097]  children CSR offsets (node space)
#define WS_CUR    16388        // int[4096]
#define WS_HI     20484        // int[4096]  node -> post index; init -1
#define WS_FLAG   24580        // int[4096]
#define WS_C1     28676        // f32[4096]
#define WS_C2     32772        // f32[4096]
#define WS_C3     36868        // f32[4096]
#define WS_C4     40964        // f32[4096]
#define WS_CLIST  45060        // int[4096]  children list (node space, for k_post)
#define WS_GP     49156        // int[4096]  post -> node id
#define WS_LOP    53252        // int[4096]  post -> subtree lo (post space)
#define WS_C3P    57348        // f32[4096]
#define WS_C4P    61444        // f32[4096]
#define WS_EPAR   65540        // int[4096]  post -> parent post (root: self)
#define WS_EWS    69636        // f32[4096]  post -> c2[parent] (root: 0)
#define WS_SP     73736        // f64[4096]  (8B aligned)
#define WS_ISP    81928        // f64[4096]
#define WS_QPP    90120        // f32[730*4096] permuted q_prime (optional)
#define WS_END    (WS_QPP + NT * N)

// qidx for PER_T=4 interleave: p -> ((p&3)<<10) | (p>>2)
__device__ __forceinline__ int qidx4(int p) { return ((p & 3) << 10) | (p >> 2); }

// ---- wave64 inclusive scan via DPP (VALU pipe; verified R6-R8, absmax 0.0) ----
template <int CTRL, int RMASK>
__device__ __forceinline__ double dpp_stage(double v) {
    union U { double d; unsigned int u[2]; };
    U s, t;
    s.d = v;
    t.u[0] = (unsigned)__builtin_amdgcn_update_dpp(0, (int)s.u[0], CTRL, RMASK, 0xf, false);
    t.u[1] = (unsigned)__builtin_amdgcn_update_dpp(0, (int)s.u[1], CTRL, RMASK, 0xf, false);
    return v + t.d;
}
__device__ __forceinline__ double wave_incl_scan(double v) {
    v = dpp_stage<0x111, 0xf>(v);   // row_shr:1
    v = dpp_stage<0x112, 0xf>(v);   // row_shr:2
    v = dpp_stage<0x114, 0xf>(v);   // row_shr:4
    v = dpp_stage<0x118, 0xf>(v);   // row_shr:8
    v = dpp_stage<0x142, 0xa>(v);   // row_bcast:15 -> rows 1,3
    v = dpp_stage<0x143, 0xc>(v);   // row_bcast:31 -> rows 2,3
    return v;
}
// inclusive scan WITHIN each 16-lane row (for the 16-wave cross-wave prefix)
__device__ __forceinline__ double row16_incl_scan(double v) {
    v = dpp_stage<0x111, 0xf>(v);
    v = dpp_stage<0x112, 0xf>(v);
    v = dpp_stage<0x114, 0xf>(v);
    v = dpp_stage<0x118, 0xf>(v);
    return v;
}
__device__ __forceinline__ double readlane_f64(double v, int slane) {
    union U { double d; int i[2]; };
    U u; u.d = v;
    U o;
    o.i[0] = __builtin_amdgcn_readlane(u.i[0], slane);
    o.i[1] = __builtin_amdgcn_readlane(u.i[1], slane);
    return o.d;
}

__global__ void k_init(int* ds, int* sz, int* ccnt, int* hi, int* flag) {
    int j = blockIdx.x * 256 + threadIdx.x;
    if (j < N) { ds[j] = N - 1; sz[j] = 1; ccnt[j] = 0; hi[j] = -1; flag[j] = 0; }
}

__global__ void k_extract(const float4* __restrict__ adj4, int* __restrict__ ds) {
    long idx = (long)blockIdx.x * 256 + threadIdx.x;
    if (idx >= (long)N * N / 4) return;
    float4 w = adj4[idx];
    long base = idx * 4;
    int row = (int)(base >> 12);
    int col = (int)(base & 4095);
    if (w.x != 0.0f) ds[col + 0] = row;
    if (w.y != 0.0f) ds[col + 1] = row;
    if (w.z != 0.0f) ds[col + 2] = row;
    if (w.w != 0.0f) ds[col + 3] = row;
}

__global__ void k_coeffs(const float* n, const float* qs, const float* ps,
                         const float* len, const float* slope, const float* width,
                         const float* xs, float* __restrict__ c1, float* __restrict__ c2,
                         float* __restrict__ c3, float* __restrict__ c4) {
    int i = blockIdx.x * 256 + threadIdx.x;
    if (i >= N) return;
    float s  = fmaxf(slope[i], 1e-4f);
    float dp = logf(width[i] / ps[i]) / logf(qs[i]);
    float v  = (1.0f / n[i]) * powf(dp, 2.0f / 3.0f) * sqrtf(s);
    float c  = fminf(fmaxf(v, 0.3f), 15.0f) * (5.0f / 3.0f);
    float k  = len[i] / c;
    float x  = xs[i];
    float denom = 2.0f * k * (1.0f - x) + DT_S;
    c1[i] = (DT_S - 2.0f * k * x) / denom;
    c2[i] = (DT_S + 2.0f * k * x) / denom;
    c3[i] = (2.0f * k * (1.0f - x) - DT_S) / denom;
    c4[i] = 2.0f * DT_S / denom;
}

__global__ void k_count(const int* __restrict__ ds, int* __restrict__ ccnt,
                        int* __restrict__ sz) {
    int u = blockIdx.x * 256 + threadIdx.x;
    if (u >= N || u == N - 1) return;
    atomicAdd(&ccnt[ds[u]], 1);
    int a = ds[u];
    while (true) {
        atomicAdd(&sz[a], 1);
        if (a == N - 1) break;
        a = ds[a];
    }
}

// single-block exclusive scan of 4096 ints
__global__ __launch_bounds__(1024) void k_scan(const int* __restrict__ src,
                                               int* __restrict__ off,
                                               int* __restrict__ cur) {
    __shared__ int buf[1024];
    int tid = threadIdx.x;
    int a0 = src[tid * 4 + 0], a1 = src[tid * 4 + 1];
    int a2 = src[tid * 4 + 2], a3 = src[tid * 4 + 3];
    int s1 = a0, s2 = a0 + a1, s3 = a0 + a1 + a2, tot = s3 + a3;
    buf[tid] = tot;
    __syncthreads();
    for (int o = 1; o < 1024; o <<= 1) {
        int add = (tid >= o) ? buf[tid - o] : 0;
        __syncthreads();
        buf[tid] += add;
        __syncthreads();
    }
    int base = buf[tid] - tot;
    off[tid * 4 + 0] = base;      cur[tid * 4 + 0] = base;
    off[tid * 4 + 1] = base + s1; cur[tid * 4 + 1] = base + s1;
    off[tid * 4 + 2] = base + s2; cur[tid * 4 + 2] = base + s2;
    off[tid * 4 + 3] = base + s3; cur[tid * 4 + 3] = base + s3;
    if (tid == 1023) off[N] = buf[1023];
}

__global__ void k_fill(const int* __restrict__ ds, int* __restrict__ cur,
                       int* __restrict__ clist) {
    int u = blockIdx.x * 256 + threadIdx.x;
    if (u >= N || u == N - 1) return;
    int cp = atomicAdd(&cur[ds[u]], 1);
    clist[cp] = u;
}

// top-down post-order interval assignment (hi = post index)
__global__ __launch_bounds__(1024) void k_post(const int* __restrict__ ds,
                                               const int* __restrict__ sz,
                                               const int* __restrict__ coff,
                                               const int* __restrict__ ccnt,
                                               const int* __restrict__ clist,
                                               int* __restrict__ hi,
                                               int* __restrict__ flag) {
    int tid = threadIdx.x;
    if (tid == 0) hi[N - 1] = N - 1;
    __syncthreads();
    for (int it = 0; it < 96; ++it) {
        for (int v = tid; v < N; v += 1024) {
            if (hi[v] >= 0 && flag[v] == 0) {
                int cum = hi[v] - sz[v] + 1;
                int b0 = coff[v], e0 = b0 + ccnt[v];
                for (int k = b0; k < e0; ++k) {
                    int c = clist[k];
                    hi[c] = cum + sz[c] - 1;
                    cum += sz[c];
                }
                flag[v] = 1;
            }
        }
        __syncthreads();
    }
}

// post-space arrays: S (ancestor c1 product, f64), lo, coeffs, parent-post, c2[par]
__global__ void k_prep(const int* __restrict__ ds, const int* __restrict__ sz,
                       const int* __restrict__ hi,
                       const float* __restrict__ c1, const float* __restrict__ c2,
                       const float* __restrict__ c3, const float* __restrict__ c4,
                       int* __restrict__ gP, int* __restrict__ loP,
                       float* __restrict__ c3P, float* __restrict__ c4P,
                       int* __restrict__ eparP, float* __restrict__ ewsP,
                       double* __restrict__ SP, double* __restrict__ ISP) {
    int u = blockIdx.x * 256 + threadIdx.x;
    if (u >= N) return;
    int p = hi[u];
    double s = 1.0;
    if (u != N - 1) {
        int a = ds[u];
        while (true) {
            s *= (double)c1[a];
            if (a == N - 1) break;
            a = ds[a];
        }
    }
    SP[p] = s; ISP[p] = 1.0 / s;
    gP[p] = u;
    loP[p] = p - sz[u] + 1;
    c3P[p] = c3[u]; c4P[p] = c4[u];
    if (u != N - 1) {
        eparP[p] = hi[ds[u]];
        ewsP[p] = c2[ds[u]];
    } else {
        eparP[p] = p;        // root: self-scatter with weight 0
        ewsP[p] = 0.0f;
    }
}

// permute q_prime into post order (coalesced write, gathered read)
__global__ void k_permute(const float* __restrict__ qp, const int* __restrict__ gP,
                          float* __restrict__ qpp) {
    long e = (long)blockIdx.x * 256 + threadIdx.x;
    if (e >= (long)NT * N) return;
    int tr = (int)(e >> 12);
    int v  = (int)(e & 4095);
    qpp[e] = qp[(size_t)tr * N + gP[v]];
}

// Persistent single-workgroup routing: 1024 threads (16 waves), 3 barriers/step.
//   A: b = CSA[s][own] + c3*q + c4*clip(ql); y=S*b; local chain + DPP wave scan;
//      wpart[wid] = wave total.                                  -- barrier 1
//   B: lane-parallel prefix of wpart (1 LDS gather + DPP row16 scan + readlane);
//      TL[qidx4(p)] = FULL prefix (woff+texw+Tloc).               -- barrier 2
//   C: prefetch next row; Tg = TL[qidx4(lo-1)]; x = b + (Tself-Tg)/S;
//      q=clip(x); zero CSA[s]; scatter into CSA[s^1]; out.       -- barrier 3
__global__ __launch_bounds__(NTH) void k_route(
    const float* __restrict__ qp, const float* __restrict__ qpp,
    const float* __restrict__ c3g, const float* __restrict__ c4g,
    const int* __restrict__ gPg, const int* __restrict__ loPg,
    const int* __restrict__ eparPg, const float* __restrict__ ewsPg,
    const double* __restrict__ SPg, const double* __restrict__ ISPg,
    int use_perm, float* __restrict__ out) {
    __shared__ float CSA[2][N];             // childsum accumulators (linear post)
    __shared__ double TL[N];                // full prefix sums, qidx4 layout
    __shared__ __align__(16) double wpart[16];
    int tid = threadIdx.x;
    int lane = tid & 63, wid = tid >> 6;
    int swid = __builtin_amdgcn_readfirstlane(wid);

    int epar[PER_T], jg[PER_T], g[PER_T];
    float ews[PER_T], c3r[PER_T], c4r[PER_T], qreg[PER_T], qc[PER_T], qn[PER_T];
    double Sr[PER_T], iSr[PER_T];
    bool haslo[PER_T];
#pragma unroll
    for (int r = 0; r < PER_T; ++r) {
        int p = tid * PER_T + r;
        epar[r] = eparPg[p]; ews[r] = ewsPg[p];
        int l = loPg[p];
        haslo[r] = (l > 0);
        int lm = (l > 0) ? (l - 1) : 0;
        jg[r] = qidx4(lm);
        g[r] = gPg[p];
        c3r[r] = c3g[p]; c4r[r] = c4g[p];
        Sr[r] = SPg[p]; iSr[r] = ISPg[p];
        float q0 = use_perm ? qpp[p] : qp[g[r]];   // row 0 raw initial state
        qreg[r] = q0; qc[r] = q0;
    }
    {   // zero both CSA buffers
        float4 z = make_float4(0.f, 0.f, 0.f, 0.f);
        *(float4*)&CSA[0][tid * PER_T] = z;
        *(float4*)&CSA[1][tid * PER_T] = z;
    }
    if (tid == NTH - 1) out[0] = fmaxf(qreg[PER_T - 1], QLB);   // root = post N-1
    __syncthreads();
    // initial scatter of q0 into buffer 1 (consumed by step t=1)
#pragma unroll
    for (int r = 0; r < PER_T; ++r)
        atomicAdd(&CSA[1][epar[r]], ews[r] * qreg[r]);
    __syncthreads();

    for (int t = 1; t < NT; ++t) {
        int s = t & 1;
        // ---- Phase A ----
        float4 ca = *(const float4*)&CSA[s][tid * PER_T];
        float cs[PER_T] = {ca.x, ca.y, ca.z, ca.w};
        float bb[PER_T];
        double yv[PER_T], Tloc[PER_T];
        double tl = 0.0;
#pragma unroll
        for (int r = 0; r < PER_T; ++r) {
            bb[r] = cs[r] + c3r[r] * qreg[r] + c4r[r] * fmaxf(qc[r], QLB);
            double y = Sr[r] * (double)bb[r];
            yv[r] = y;
            tl += y;
            Tloc[r] = tl;
        }
        double incl = wave_incl_scan(tl);              // VALU only
        double texw = incl - tl;                       // within-wave excl prefix
        if (lane == 63) wpart[wid] = incl;
        __syncthreads();                               // barrier 1
        // ---- Phase B: cross-wave prefix, lane-parallel ----
        double wpown = wpart[lane & 15];               // 1 ds_read_b64 (broadcast x4)
        double wincl = row16_incl_scan(wpown);         // prefix over 16 waves
        double woff = readlane_f64(wincl, swid) - readlane_f64(wpown, swid);
        double tbase = woff + texw;
#pragma unroll
        for (int r = 0; r < PER_T; ++r)
            TL[(r << 10) | tid] = tbase + Tloc[r];     // full prefix published
        __syncthreads();                               // barrier 2
        // ---- Phase C ----
        if (t < NT - 1) {                              // prefetch next lateral row
            if (use_perm) {
                float4 a = ((const float4*)(qpp + (size_t)t * N))[tid];
                qn[0] = a.x; qn[1] = a.y; qn[2] = a.z; qn[3] = a.w;
            } else {
                const float* row = qp + (size_t)t * N;
#pragma unroll
                for (int r = 0; r < PER_T; ++r) qn[r] = row[g[r]];
            }
        }
#pragma unroll
        for (int r = 0; r < PER_T; ++r) {
            double Tg = haslo[r] ? TL[jg[r]] : 0.0;
            double Tself = tbase + Tloc[r] - yv[r];
            double x = (double)bb[r] + (Tself - Tg) * iSr[r];
            qreg[r] = fmaxf((float)x, QLB);
        }
        {   // reset consumed buffer (reused at step t+2)
            float4 z = make_float4(0.f, 0.f, 0.f, 0.f);
            *(float4*)&CSA[s][tid * PER_T] = z;
        }
#pragma unroll
        for (int r = 0; r < PER_T; ++r)                // push into next buffer
            atomicAdd(&CSA[s ^ 1][epar[r]], ews[r] * qreg[r]);
        if (tid == NTH - 1) out[t] = qreg[PER_T - 1];
        __syncthreads();                               // barrier 3
#pragma unroll
        for (int r = 0; r < PER_T; ++r) qc[r] = qn[r];
    }
}

extern "C" void kernel_launch(void* const* d_in, const int* in_sizes, int n_in,
                              void* d_out, int out_size, void* d_ws, size_t ws_size,
                              hipStream_t stream) {
    const float* qp    = (const float*)d_in[0];   // [730,4096]
    const float* n     = (const float*)d_in[1];
    const float* qs    = (const float*)d_in[2];
    const float* ps    = (const float*)d_in[3];
    const float* len   = (const float*)d_in[4];
    const float* slope = (const float*)d_in[5];
    const float* width = (const float*)d_in[6];
    const float* xs    = (const float*)d_in[7];
    const float* adj   = (const float*)d_in[8];   // [4096,4096]
    float* out = (float*)d_out;

    int*    W     = (int*)d_ws;
    int*    ds    = W + WS_DS;
    int*    sz    = W + WS_SZ;
    int*    ccnt  = W + WS_CCNT;
    int*    coff  = W + WS_COFF;
    int*    cur   = W + WS_CUR;
    int*    hi    = W + WS_HI;
    int*    flag  = W + WS_FLAG;
    float*  c1    = (float*)(W + WS_C1);
    float*  c2    = (float*)(W + WS_C2);
    float*  c3    = (float*)(W + WS_C3);
    float*  c4    = (float*)(W + WS_C4);
    int*    clist = W + WS_CLIST;
    int*    gP    = W + WS_GP;
    int*    loP   = W + WS_LOP;
    float*  c3P   = (float*)(W + WS_C3P);
    float*  c4P   = (float*)(W + WS_C4P);
    int*    eparP = W + WS_EPAR;
    float*  ewsP  = (float*)(W + WS_EWS);
    double* SP    = (double*)(W + WS_SP);
    double* ISP   = (double*)(W + WS_ISP);
    float*  QPP   = (float*)(W + WS_QPP);

    int use_perm = (ws_size >= (size_t)WS_END * 4) ? 1 : 0;

    k_init<<<(N + 255) / 256, 256, 0, stream>>>(ds, sz, ccnt, hi, flag);
    k_extract<<<(N * N / 4 + 255) / 256, 256, 0, stream>>>((const float4*)adj, ds);
    k_coeffs<<<(N + 255) / 256, 256, 0, stream>>>(n, qs, ps, len, slope, width, xs,
                                                  c1, c2, c3, c4);
    k_count<<<(N + 255) / 256, 256, 0, stream>>>(ds, ccnt, sz);
    k_scan<<<1, 1024, 0, stream>>>(ccnt, coff, cur);
    k_fill<<<(N + 255) / 256, 256, 0, stream>>>(ds, cur, clist);
    k_post<<<1, 1024, 0, stream>>>(ds, sz, coff, ccnt, clist, hi, flag);
    k_prep<<<(N + 255) / 256, 256, 0, stream>>>(ds, sz, hi, c1, c2, c3, c4,
                                                gP, loP, c3P, c4P, eparP, ewsP,
                                                SP, ISP);
    if (use_perm)
        k_permute<<<(int)(((long)NT * N + 255) / 256), 256, 0, stream>>>(qp, gP, QPP);
    k_route<<<1, NTH, 0, stream>>>(qp, QPP, c3P, c4P, gP, loP, eparP, ewsP,
                                   SP, ISP, use_perm, out);
}